// Round 3
// baseline (95.243 us; speedup 1.0000x reference)
//
#include <hip/hip_runtime.h>

typedef __attribute__((ext_vector_type(8))) short          bf16x8;   // MFMA A/B frag
typedef __attribute__((ext_vector_type(8))) unsigned short u16x8;
typedef __attribute__((ext_vector_type(4))) float          f32x4;    // MFMA C/D frag

#define Bn 16
#define IC 32
#define OC 64
#define Hh 128
#define Ww 128
#define ROWS 4            // output rows per block
#define INROWS (ROWS + 2) // staged rows incl. halo
#define CP 130            // staged cols: col c <-> gx = c-1  (gx -1..128)

__device__ inline unsigned short f2b(float f) {
    unsigned u = __builtin_bit_cast(unsigned, f);
    return (unsigned short)((u + 0x7FFFu + ((u >> 16) & 1u)) >> 16);
}

// ---- prep 1: x NCHW fp32 -> NHWC bf16 (d_ws) ----------------------------
// block = one (b,y) row; thread t: px = t>>1, half = t&1 handles 16 ic.
__global__ void prep_x(const float* __restrict__ x, unsigned short* __restrict__ xb)
{
    const int b  = blockIdx.y, y = blockIdx.x;
    const int t  = threadIdx.x;
    const int px = t >> 1, part = t & 1;

    const float* src = x + (((size_t)(b * IC + part * 16)) * Hh + y) * Ww + px;
    unsigned short v[16];
    #pragma unroll
    for (int j = 0; j < 16; ++j) v[j] = f2b(src[(size_t)j * Hh * Ww]);

    unsigned short* dst = xb + (((size_t)b * Hh + y) * Ww + px) * IC + part * 16;
    *(u16x8*)dst       = *(const u16x8*)&v[0];
    *(u16x8*)(dst + 8) = *(const u16x8*)&v[8];
}

// ---- prep 2: w OIHW fp32 -> bf16 [dydx][oc][ic] (d_ws tail) -------------
__global__ void prep_w(const float* __restrict__ w, unsigned short* __restrict__ wf)
{
    int idx = blockIdx.x * 256 + threadIdx.x;        // 0 .. 18431
    int dydx = idx / (OC * IC);
    int rem  = idx - dydx * (OC * IC);               // oc*32 + ic
    wf[idx] = f2b(w[(size_t)rem * 9 + dydx]);
}

// ---- main: implicit GEMM, 9 shifted K=32 MFMAs + fused min --------------
__global__ __launch_bounds__(256, 2)
void conv_main(const unsigned short* __restrict__ xb,
               const unsigned short* __restrict__ wf,
               const float* __restrict__ bias,
               float* __restrict__ out)
{
    // LDS: [row 0..5][col 0..129][ic 0..31] bf16 = 49920 B
    __shared__ __align__(16) unsigned short xs[INROWS * CP * IC];

    const int tid  = threadIdx.x;
    const int lane = tid & 63;
    const int wid  = tid >> 6;
    const int llo  = lane & 15;
    const int lhi  = lane >> 4;
    const int b    = blockIdx.y;
    const int y0   = blockIdx.x * ROWS;

    // B-fragments straight from the pre-transposed table (L2-resident).
    bf16x8 bw[9][4];
    #pragma unroll
    for (int dydx = 0; dydx < 9; ++dydx)
        #pragma unroll
        for (int nf = 0; nf < 4; ++nf)
            bw[dydx][nf] = *(const bf16x8*)&wf[((dydx * 4 + nf) * 16 + llo) * IC + lhi * 8];

    float bias_s[4];
    #pragma unroll
    for (int nf = 0; nf < 4; ++nf) bias_s[nf] = bias[nf * 16 + llo];

    const u16x8 z8 = (u16x8){0,0,0,0,0,0,0,0};

    // zero halo columns (col 0 and 129): 6 rows x 2 cols x 4 chunks of 16B
    if (tid < 48) {
        int r = tid >> 3, rest = tid & 7;
        int col = (rest >> 2) ? (CP - 1) : 0;
        *(u16x8*)&xs[(r * CP + col) * IC + (rest & 3) * 8] = z8;
    }
    // zero out-of-image rows (top/bottom edge blocks only)
    #pragma unroll
    for (int rr = 0; rr < INROWS; ++rr) {
        int gy = y0 - 1 + rr;
        if ((unsigned)gy >= 128u) {
            for (int i = tid; i < Ww * IC / 8; i += 256)
                *(u16x8*)&xs[(rr * CP + 1) * IC + i * 8] = z8;
        }
    }

    // stage valid rows: 8KB/row, contiguous NHWC -> linear LDS via global_load_lds
    for (int rr = wid; rr < INROWS; rr += 4) {
        int gy = y0 - 1 + rr;
        if ((unsigned)gy < 128u) {
            const char* src = (const char*)(xb + (((size_t)b * Hh + gy) * Ww) * IC);
            char* ldst = (char*)&xs[(rr * CP + 1) * IC];
            #pragma unroll
            for (int k = 0; k < 8; ++k)
                __builtin_amdgcn_global_load_lds(src + k * 1024 + lane * 16,
                                                 ldst + k * 1024, 16, 0, 0);
        }
    }
    __syncthreads();

    const int px0 = wid * 32;
    for (int r = 0; r < ROWS; ++r) {
        f32x4 acc[2][4];
        #pragma unroll
        for (int m = 0; m < 2; ++m)
            #pragma unroll
            for (int nf = 0; nf < 4; ++nf)
                acc[m][nf] = (f32x4){0.f, 0.f, 0.f, 0.f};

        #pragma unroll
        for (int dy = 0; dy < 3; ++dy) {
            #pragma unroll
            for (int dx = 0; dx < 3; ++dx) {
                const int dydx = dy * 3 + dx;
                bf16x8 a0 = *(const bf16x8*)&xs[((r + dy) * CP + px0 + llo + dx) * IC + lhi * 8];
                bf16x8 a1 = *(const bf16x8*)&xs[((r + dy) * CP + px0 + 16 + llo + dx) * IC + lhi * 8];
                #pragma unroll
                for (int nf = 0; nf < 4; ++nf) {
                    acc[0][nf] = __builtin_amdgcn_mfma_f32_16x16x32_bf16(a0, bw[dydx][nf], acc[0][nf], 0, 0, 0);
                    acc[1][nf] = __builtin_amdgcn_mfma_f32_16x16x32_bf16(a1, bw[dydx][nf], acc[1][nf], 0, 0, 0);
                }
            }
        }

        // epilogue: bias, min over 64 oc (4 frags in-reg + 4 shfl over oc-lanes), x2
        #pragma unroll
        for (int m = 0; m < 2; ++m) {
            f32x4 vout;
            #pragma unroll
            for (int j = 0; j < 4; ++j) {
                float v = fminf(fminf(acc[m][0][j] + bias_s[0], acc[m][1][j] + bias_s[1]),
                                fminf(acc[m][2][j] + bias_s[2], acc[m][3][j] + bias_s[3]));
                v = fminf(v, __shfl_xor(v, 1, 64));
                v = fminf(v, __shfl_xor(v, 2, 64));
                v = fminf(v, __shfl_xor(v, 4, 64));
                v = fminf(v, __shfl_xor(v, 8, 64));
                vout[j] = v * 2.0f;
            }
            if (llo == 0) {
                float* op = out + ((size_t)b * Hh + (y0 + r)) * Ww + px0 + m * 16 + lhi * 4;
                *(f32x4*)op = vout;
            }
        }
    }
}

extern "C" void kernel_launch(void* const* d_in, const int* in_sizes, int n_in,
                              void* d_out, int out_size, void* d_ws, size_t ws_size,
                              hipStream_t stream)
{
    const float* x    = (const float*)d_in[0];
    const float* w    = (const float*)d_in[1];
    const float* bias = (const float*)d_in[2];
    float* out        = (float*)d_out;

    unsigned short* xb = (unsigned short*)d_ws;                       // 16 MB
    unsigned short* wfr = xb + (size_t)Bn * Hh * Ww * IC;             // +36 KB

    prep_x<<<dim3(Hh, Bn), 256, 0, stream>>>(x, xb);
    prep_w<<<dim3(9 * OC * IC / 256), 256, 0, stream>>>(w, wfr);
    conv_main<<<dim3(Hh / ROWS, Bn), 256, 0, stream>>>(xb, wfr, bias, out);
}

// Round 4
// 90.477 us; speedup vs baseline: 1.0527x; 1.0527x over previous
//
#include <hip/hip_runtime.h>

typedef __attribute__((ext_vector_type(8))) short          bf16x8;   // MFMA A/B frag
typedef __attribute__((ext_vector_type(8))) unsigned short u16x8;
typedef __attribute__((ext_vector_type(4))) float          f32x4;    // MFMA C/D frag

#define Bn 16
#define IC 32
#define OC 64
#define Hh 128
#define Ww 128
#define ROWS 4            // output rows per block
#define INROWS (ROWS + 2) // staged rows incl. halo
#define CP 130            // staged cols: col c <-> gx = c-1

__device__ inline unsigned short f2b(float f) {
    unsigned u = __builtin_bit_cast(unsigned, f);
    return (unsigned short)((u + 0x7FFFu + ((u >> 16) & 1u)) >> 16);
}

// ---- prep: w OIHW fp32 -> bf16 [dydx][oc][ic] frag table (36 KB, L2) ----
__global__ void prep_w(const float* __restrict__ w, unsigned short* __restrict__ wf)
{
    int idx = blockIdx.x * 256 + threadIdx.x;        // 0 .. 18431
    int dydx = idx / (OC * IC);
    int rem  = idx - dydx * (OC * IC);               // oc*32 + ic
    wf[idx] = f2b(w[(size_t)rem * 9 + dydx]);
}

// ---- fused: NCHW fp32 -> LDS bf16 stage, 9 shifted K=32 MFMAs, min ------
__global__ __launch_bounds__(256, 2)
void conv_fused(const float* __restrict__ x,
                const unsigned short* __restrict__ wf,
                const float* __restrict__ bias,
                float* __restrict__ out)
{
    // LDS: [row 0..5][col 0..129][ic 0..31] bf16 = 49920 B
    __shared__ __align__(16) unsigned short xs[INROWS * CP * IC];

    const int tid  = threadIdx.x;
    const int lane = tid & 63;
    const int wid  = tid >> 6;
    const int llo  = lane & 15;
    const int lhi  = lane >> 4;
    const int b    = blockIdx.y;
    const int y0   = blockIdx.x * ROWS;

    // B-fragments from the pre-transposed bf16 table (L2-resident, 36 KB).
    bf16x8 bw[9][4];
    #pragma unroll
    for (int dydx = 0; dydx < 9; ++dydx)
        #pragma unroll
        for (int nf = 0; nf < 4; ++nf)
            bw[dydx][nf] = *(const bf16x8*)&wf[((dydx * 4 + nf) * 16 + llo) * IC + lhi * 8];

    float bias_s[4];
    #pragma unroll
    for (int nf = 0; nf < 4; ++nf) bias_s[nf] = bias[nf * 16 + llo];

    // zero halo columns (gx = -1 and 128): 6 rows x 2 cols x 4 chunks
    if (tid < 48) {
        int r = tid >> 3, rest = tid & 7;
        int col = (rest >> 2) ? (CP - 1) : 0;
        *(u16x8*)&xs[(r * CP + col) * IC + (rest & 3) * 8] = (u16x8){0,0,0,0,0,0,0,0};
    }

    // stage: task = (row,icg,col); lane -> consecutive col => 256B coalesced
    // fp32 reads; 8 channels/task converted + packed to one ds_write_b128.
    // Out-of-image rows (top/bottom blocks) write zeros in the same loop.
    const float* xb0 = x + (size_t)b * IC * Hh * Ww;
    #pragma unroll
    for (int i = 0; i < 12; ++i) {                    // 6*4*128 / 256 = 12
        int task = tid + i * 256;
        int col  = task & 127;                        // gx
        int rg   = task >> 7;                         // row*4 + icg
        int icg  = rg & 3;
        int row  = rg >> 2;
        int gy   = y0 - 1 + row;
        u16x8 pk = (u16x8){0,0,0,0,0,0,0,0};
        if ((unsigned)gy < 128u) {
            const float* sp = xb0 + ((size_t)(icg * 8) * Hh + gy) * Ww + col;
            #pragma unroll
            for (int j = 0; j < 8; ++j) pk[j] = f2b(sp[(size_t)j * Hh * Ww]);
        }
        *(u16x8*)&xs[(row * CP + col + 1) * IC + icg * 8] = pk;
    }
    __syncthreads();

    const int px0 = wid * 32;
    for (int r = 0; r < ROWS; ++r) {
        f32x4 acc[2][4];
        #pragma unroll
        for (int m = 0; m < 2; ++m)
            #pragma unroll
            for (int nf = 0; nf < 4; ++nf)
                acc[m][nf] = (f32x4){0.f, 0.f, 0.f, 0.f};

        #pragma unroll
        for (int dy = 0; dy < 3; ++dy) {
            #pragma unroll
            for (int dx = 0; dx < 3; ++dx) {
                const int dydx = dy * 3 + dx;
                bf16x8 a0 = *(const bf16x8*)&xs[((r + dy) * CP + px0 + llo + dx) * IC + lhi * 8];
                bf16x8 a1 = *(const bf16x8*)&xs[((r + dy) * CP + px0 + 16 + llo + dx) * IC + lhi * 8];
                #pragma unroll
                for (int nf = 0; nf < 4; ++nf) {
                    acc[0][nf] = __builtin_amdgcn_mfma_f32_16x16x32_bf16(a0, bw[dydx][nf], acc[0][nf], 0, 0, 0);
                    acc[1][nf] = __builtin_amdgcn_mfma_f32_16x16x32_bf16(a1, bw[dydx][nf], acc[1][nf], 0, 0, 0);
                }
            }
        }

        // epilogue: bias, min over 64 oc (in-reg + 4 shfl over oc-lanes), x2
        #pragma unroll
        for (int m = 0; m < 2; ++m) {
            f32x4 vout;
            #pragma unroll
            for (int j = 0; j < 4; ++j) {
                float v = fminf(fminf(acc[m][0][j] + bias_s[0], acc[m][1][j] + bias_s[1]),
                                fminf(acc[m][2][j] + bias_s[2], acc[m][3][j] + bias_s[3]));
                v = fminf(v, __shfl_xor(v, 1, 64));
                v = fminf(v, __shfl_xor(v, 2, 64));
                v = fminf(v, __shfl_xor(v, 4, 64));
                v = fminf(v, __shfl_xor(v, 8, 64));
                vout[j] = v * 2.0f;
            }
            if (llo == 0) {
                float* op = out + ((size_t)b * Hh + (y0 + r)) * Ww + px0 + m * 16 + lhi * 4;
                *(f32x4*)op = vout;
            }
        }
    }
}

extern "C" void kernel_launch(void* const* d_in, const int* in_sizes, int n_in,
                              void* d_out, int out_size, void* d_ws, size_t ws_size,
                              hipStream_t stream)
{
    const float* x    = (const float*)d_in[0];
    const float* w    = (const float*)d_in[1];
    const float* bias = (const float*)d_in[2];
    float* out        = (float*)d_out;

    unsigned short* wfr = (unsigned short*)d_ws;      // 36 KB frag table

    prep_w<<<dim3(9 * OC * IC / 256), 256, 0, stream>>>(w, wfr);
    conv_fused<<<dim3(Hh / ROWS, Bn), 256, 0, stream>>>(x, wfr, bias, out);
}

// Round 5
// 88.113 us; speedup vs baseline: 1.0809x; 1.0268x over previous
//
#include <hip/hip_runtime.h>

typedef __attribute__((ext_vector_type(8))) short          bf16x8;   // MFMA A/B frag
typedef __attribute__((ext_vector_type(8))) unsigned short u16x8;
typedef __attribute__((ext_vector_type(4))) float          f32x4;    // MFMA C/D frag

#define Bn 16
#define IC 32
#define OC 64
#define Hh 128
#define Ww 128
#define ROWS 4            // output rows per block
#define INROWS (ROWS + 2) // staged rows incl. halo
#define CP 132            // padded col count; LDS col = gx+1, cols 0..129 used

__device__ inline unsigned short f2b(float f) {
    unsigned u = __builtin_bit_cast(unsigned, f);
    return (unsigned short)((u + 0x7FFFu + ((u >> 16) & 1u)) >> 16);
}

// pack two fp32 -> two bf16 in one instr (low = a, high = b)
__device__ inline unsigned cvtpk(float a, float b) {
    unsigned r;
    asm("v_cvt_pk_bf16_f32 %0, %1, %2" : "=v"(r) : "v"(a), "v"(b));
    return r;
}

// ---- prep: w OIHW fp32 -> bf16 [dydx][oc][ic] frag table (36 KB, L2) ----
__global__ void prep_w(const float* __restrict__ w, unsigned short* __restrict__ wf)
{
    int idx = blockIdx.x * 256 + threadIdx.x;        // 0 .. 18431
    int dydx = idx / (OC * IC);
    int rem  = idx - dydx * (OC * IC);               // oc*32 + ic
    wf[idx] = f2b(w[(size_t)rem * 9 + dydx]);
}

// ---- fused: NCHW fp32 -> LDS bf16 (vectorized), 9 shifted MFMAs, min ----
// LDS layout [row 0..5][icg 0..3][col 0..131][ic8 0..7]:
//   - staging ds_write_b128: lanes at 16B stride within a (row,icg) panel -> clean
//   - A-frag ds_read_b128: 16-lane groups contiguous 256B, lhi panels offset
//     by 2112B (slot+4) -> balanced 8-phase, no excess conflicts
__global__ __launch_bounds__(256, 2)
void conv_fused(const float* __restrict__ x,
                const unsigned short* __restrict__ wf,
                const float* __restrict__ bias,
                float* __restrict__ out)
{
    __shared__ __align__(16) unsigned short xs[INROWS * 4 * CP * 8]; // 50688 B

    const int tid  = threadIdx.x;
    const int lane = tid & 63;
    const int wid  = tid >> 6;
    const int llo  = lane & 15;
    const int lhi  = lane >> 4;
    const int b    = blockIdx.y;
    const int y0   = blockIdx.x * ROWS;

    // zero halo columns (gx = -1 -> col 0, gx = 128 -> col 129)
    if (tid < 48) {
        int r = tid >> 3, rest = tid & 7;
        int icg = rest & 3;
        int col = (rest >> 2) ? 129 : 0;
        *(u16x8*)&xs[((r * 4 + icg) * CP + col) * 8] = (u16x8){0,0,0,0,0,0,0,0};
    }

    // ---- stage: task = (row, icg, 4-col group); 8x dwordx4 loads,
    //      16x cvt_pk, 4x ds_write_b128 per task; 3 tasks/thread ----
    const float* xb0 = x + (size_t)b * IC * Hh * Ww;
    #pragma unroll
    for (int i = 0; i < 3; ++i) {                     // 6*4*32 / 256 = 3
        int task = tid + i * 256;
        int cg   = task & 31;                         // 4-col group
        int icg  = (task >> 5) & 3;
        int row  = task >> 7;
        int gy   = y0 - 1 + row;
        int col0 = cg * 4;

        f32x4 v[8];
        if ((unsigned)gy < 128u) {
            const float* sp = xb0 + ((size_t)(icg * 8) * Hh + gy) * Ww + col0;
            #pragma unroll
            for (int j = 0; j < 8; ++j)
                v[j] = *(const f32x4*)(sp + (size_t)j * Hh * Ww);
        } else {
            #pragma unroll
            for (int j = 0; j < 8; ++j) v[j] = (f32x4){0.f, 0.f, 0.f, 0.f};
        }

        unsigned short* base = &xs[((row * 4 + icg) * CP + col0 + 1) * 8];
        #pragma unroll
        for (int c = 0; c < 4; ++c) {
            unsigned pk[4];
            #pragma unroll
            for (int jp = 0; jp < 4; ++jp)
                pk[jp] = cvtpk(v[2 * jp][c], v[2 * jp + 1][c]);
            *(u16x8*)(base + c * 8) = *(const u16x8*)&pk[0];
        }
    }

    // B-fragments from pre-transposed table (issued after staging loads,
    // overlaps their latency; 36 KB table is L2-resident)
    bf16x8 bw[9][4];
    #pragma unroll
    for (int dydx = 0; dydx < 9; ++dydx)
        #pragma unroll
        for (int nf = 0; nf < 4; ++nf)
            bw[dydx][nf] = *(const bf16x8*)&wf[((dydx * 4 + nf) * 16 + llo) * IC + lhi * 8];

    float bias_s[4];
    #pragma unroll
    for (int nf = 0; nf < 4; ++nf) bias_s[nf] = bias[nf * 16 + llo];

    __syncthreads();

    const int px0 = wid * 32;
    for (int r = 0; r < ROWS; ++r) {
        f32x4 acc[2][4];
        #pragma unroll
        for (int m = 0; m < 2; ++m)
            #pragma unroll
            for (int nf = 0; nf < 4; ++nf)
                acc[m][nf] = (f32x4){0.f, 0.f, 0.f, 0.f};

        #pragma unroll
        for (int dy = 0; dy < 3; ++dy) {
            #pragma unroll
            for (int dx = 0; dx < 3; ++dx) {
                const int dydx = dy * 3 + dx;
                bf16x8 a0 = *(const bf16x8*)&xs[(((r + dy) * 4 + lhi) * CP + px0 + llo + dx) * 8];
                bf16x8 a1 = *(const bf16x8*)&xs[(((r + dy) * 4 + lhi) * CP + px0 + 16 + llo + dx) * 8];
                #pragma unroll
                for (int nf = 0; nf < 4; ++nf) {
                    acc[0][nf] = __builtin_amdgcn_mfma_f32_16x16x32_bf16(a0, bw[dydx][nf], acc[0][nf], 0, 0, 0);
                    acc[1][nf] = __builtin_amdgcn_mfma_f32_16x16x32_bf16(a1, bw[dydx][nf], acc[1][nf], 0, 0, 0);
                }
            }
        }

        // epilogue: bias, min over 64 oc (4 frags in-reg + 4 shfl), x2, store
        #pragma unroll
        for (int m = 0; m < 2; ++m) {
            f32x4 vout;
            #pragma unroll
            for (int j = 0; j < 4; ++j) {
                float v = fminf(fminf(acc[m][0][j] + bias_s[0], acc[m][1][j] + bias_s[1]),
                                fminf(acc[m][2][j] + bias_s[2], acc[m][3][j] + bias_s[3]));
                v = fminf(v, __shfl_xor(v, 1, 64));
                v = fminf(v, __shfl_xor(v, 2, 64));
                v = fminf(v, __shfl_xor(v, 4, 64));
                v = fminf(v, __shfl_xor(v, 8, 64));
                vout[j] = v * 2.0f;
            }
            if (llo == 0) {
                float* op = out + ((size_t)b * Hh + (y0 + r)) * Ww + px0 + m * 16 + lhi * 4;
                *(f32x4*)op = vout;
            }
        }
    }
}

extern "C" void kernel_launch(void* const* d_in, const int* in_sizes, int n_in,
                              void* d_out, int out_size, void* d_ws, size_t ws_size,
                              hipStream_t stream)
{
    const float* x    = (const float*)d_in[0];
    const float* w    = (const float*)d_in[1];
    const float* bias = (const float*)d_in[2];
    float* out        = (float*)d_out;

    unsigned short* wfr = (unsigned short*)d_ws;      // 36 KB frag table

    prep_w<<<dim3(9 * OC * IC / 256), 256, 0, stream>>>(w, wfr);
    conv_fused<<<dim3(Hh / ROWS, Bn), 256, 0, stream>>>(x, wfr, bias, out);
}